// Round 1
// baseline (208.366 us; speedup 1.0000x reference)
//
#include <hip/hip_runtime.h>

// Sizes (fixed by the problem)
#define B_  32
#define TE_ 8192
#define H_  128
#define M_  (B_ * TE_)   // 262144 rows

typedef __bf16 bf16x8 __attribute__((ext_vector_type(8)));
typedef __bf16 bf16x4 __attribute__((ext_vector_type(4)));
typedef float  f32x4  __attribute__((ext_vector_type(4)));

// ws layout (floats): per-block partials, written before read every run.
// PL[1024] (per-block L) | PC[1024*128] (per-block context partial)
#define WS_PL 0
#define WS_PC 1024

// LDS strip buffer: 16 rows x 256 B (bf16 row) + 16 B pad -> 272 B row stride
#define SROW 272

__device__ __forceinline__ float tanh_fast(float x) {
  x = fminf(10.f, fmaxf(-10.f, x));
  float e = __expf(2.f * x);
  return (e - 1.f) * __builtin_amdgcn_rcpf(e + 1.f);
}

// ---------------------------------------------------------------------------
// Fused kernel (1024 blocks, 256 thr, 3 blk/CU): prep folded into prologue.
//   prologue (hidden under strip-0 enc loads, ~900 cyc of otherwise-idle VMEM
//   latency): pack W fp32->bf16 into ldsW in MFMA A-fragment order, and
//   compute Uh[b] = dec[b].U as a split 2x64 dot (U is L2-resident after the
//   first block round; 64 KB/block of L2 traffic).
//   main loop: unchanged 4 strips x 16 rows/wave, lane-contiguous nontemporal
//   float4 loads -> bf16 -> LDS scatter (272B stride) -> ds_read_b128
//   fragments -> 32x mfma_16x16x32 -> tanh -> V dot -> w = exp(score).
//   epilogue: per-block partial L and C stored to private ws slots (NO
//   atomics, no zero-init dependency).
// A-fragment pack layout (consumed as ldsW[(nt*4+s)*64+lane], 8 bf16 each):
//   bf16 elem E(k,n) = ((n>>4)*4+(k>>5))*512 + (((k>>3)&3)*16+(n&15))*8 + (k&7)
//   pack writes pairs (k even, k+1) as one b32: E(k+1,n) == E(k,n)+1.
// ---------------------------------------------------------------------------
__global__ __launch_bounds__(256, 3) void fused_kernel(
    const float* __restrict__ enc, const float* __restrict__ dec,
    const float* __restrict__ W, const float* __restrict__ U,
    const float* __restrict__ V, float* __restrict__ wout,
    float* __restrict__ ws) {
  __shared__ uint4 ldsW[2048];      // 32 KB packed W; reused as pcbuf at end
  __shared__ float ldsUV[256];      // u[128] | v[128]
  __shared__ float lsum[4];
  __shared__ __align__(16) unsigned char ldsS[4][16 * SROW];  // 17 KB strips

  int t = threadIdx.x, wave = t >> 6, lane = t & 63;
  int l15 = lane & 15, quad = lane >> 4;
  int blockRow = blockIdx.x << 8;   // 256 rows/block, batch-aligned
  int b = blockRow >> 13;

  // issue strip-0 enc loads FIRST (in flight across the whole prologue)
  const char* gbase = (const char*)enc + (size_t)(blockRow + (wave << 4)) * (H_ * 4);
  f32x4 ld[8];
  #pragma unroll
  for (int i = 0; i < 8; ++i)
    ld[i] = __builtin_nontemporal_load((const f32x4*)(gbase + i * 1024 + lane * 16));

  // --- prologue A: stage dec row; pack W -> ldsW (bf16, fragment order) ---
  // scratch aliased onto the (not-yet-used) strip buffers
  float* ldsP = (float*)ldsS;          // 256 floats: Uh half-dots
  float* ldsd = ((float*)ldsS) + 256;  // 128 floats: dec[b]
  if (t < 32) ((float4*)ldsd)[t] = ((const float4*)(dec + b * H_))[t];
  {
    unsigned int* w32 = (unsigned int*)ldsW;
    int c32 = t & 31, r8 = t >> 5;     // float4-column, row-pair index
    #pragma unroll
    for (int p = 0; p < 8; ++p) {
      int kA = p * 16 + r8 * 2;        // even rows 0..126, each exactly once
      float4 rA = ((const float4*)(W + kA * H_))[c32];
      float4 rB = ((const float4*)(W + (kA + 1) * H_))[c32];
      float fa[4] = {rA.x, rA.y, rA.z, rA.w};
      float fb[4] = {rB.x, rB.y, rB.z, rB.w};
      #pragma unroll
      for (int c = 0; c < 4; ++c) {
        int n = c32 * 4 + c;
        union { __bf16 h[2]; unsigned int u; } pk;
        pk.h[0] = (__bf16)fa[c]; pk.h[1] = (__bf16)fb[c];
        int E = ((n >> 4) * 4 + (kA >> 5)) * 512
              + (((kA >> 3) & 3) * 16 + (n & 15)) * 8 + (kA & 7);
        w32[E >> 1] = pk.u;            // E even -> aligned b32, (k, k+1) pair
      }
    }
  }
  __syncthreads();

  // --- prologue B: Uh[b] = dec[b] . U, split over two 64-term halves ---
  {
    int col = t & 127, half = t >> 7;
    const float* Up = U + (half * 64) * H_ + col;   // coalesced across col
    const float* dp = ldsd + half * 64;
    float s = 0.f;
    #pragma unroll
    for (int h = 0; h < 64; ++h) s += dp[h] * Up[h * H_];
    ldsP[t] = s;
  }
  __syncthreads();
  if (t < 128) ldsUV[t] = ldsP[t] + ldsP[t + 128];
  else ldsUV[t] = V[t - 128];
  __syncthreads();

  float cacc[32];
  #pragma unroll
  for (int k = 0; k < 32; ++k) cacc[k] = 0.f;
  float Lpart = 0.f;

  unsigned char* sb = ldsS[wave];
  int wrhi = lane >> 5, wc = lane & 31;   // write row parity / 8B-chunk

  #pragma unroll
  for (int it = 0; it < 4; ++it) {
    // cvt current strip to bf16 (waits on its loads)
    uint2 hp[8];
    #pragma unroll
    for (int i = 0; i < 8; ++i) {
      union { bf16x4 h; uint2 u; } cv;
      cv.h[0] = (__bf16)ld[i][0]; cv.h[1] = (__bf16)ld[i][1];
      cv.h[2] = (__bf16)ld[i][2]; cv.h[3] = (__bf16)ld[i][3];
      hp[i] = cv.u;
    }
    // issue next strip's loads (in flight across LDS + MFMA + epilogue)
    if (it < 3) {
      #pragma unroll
      for (int i = 0; i < 8; ++i)
        ld[i] = __builtin_nontemporal_load(
            (const f32x4*)(gbase + (it + 1) * 32768 + i * 1024 + lane * 16));
    }
    // scatter to LDS: piece i = row 2i+wrhi, bytes [wc*8, wc*8+8)
    #pragma unroll
    for (int i = 0; i < 8; ++i)
      *(uint2*)(sb + (2 * i + wrhi) * SROW + wc * 8) = hp[i];

    // read MFMA B-fragments: af[s] = row l15, cols s*32+quad*8..+7 (bf16)
    bf16x8 af[4];
    #pragma unroll
    for (int s = 0; s < 4; ++s)
      af[s] = *(const bf16x8*)(sb + l15 * SROW + s * 64 + quad * 16);

    float p = 0.f;
    #pragma unroll
    for (int nt = 0; nt < 8; ++nt) {
      f32x4 acc = {0.f, 0.f, 0.f, 0.f};
      #pragma unroll
      for (int s = 0; s < 4; ++s) {
        union { uint4 u; bf16x8 v; } bw;
        bw.u = ldsW[(nt * 4 + s) * 64 + lane];
        acc = __builtin_amdgcn_mfma_f32_16x16x32_bf16(bw.v, af[s], acc, 0, 0, 0);
      }
      float4 u4 = ((const float4*)ldsUV)[nt * 4 + quad];
      float4 v4 = ((const float4*)(ldsUV + 128))[nt * 4 + quad];
      p += tanh_fast(acc[0] + u4.x) * v4.x;
      p += tanh_fast(acc[1] + u4.y) * v4.y;
      p += tanh_fast(acc[2] + u4.z) * v4.z;
      p += tanh_fast(acc[3] + u4.w) * v4.w;
    }
    // sum the 4 quads -> full score for row l15 in every lane
    p += __shfl_xor(p, 16, 64);
    p += __shfl_xor(p, 32, 64);
    float w = __expf(p);   // safe: |score| <= ||V||_1 * 1 ~ 5

    int rowBase = blockRow + ((it * 4 + wave) << 4);
    if (quad == 0) wout[rowBase + l15] = w;   // contiguous 64B line
    Lpart += w;                                // l15 distinct; quads duplicate

    // context: this lane's af row IS row l15 -> weight is w directly
    #pragma unroll
    for (int s = 0; s < 4; ++s)
      #pragma unroll
      for (int j = 0; j < 8; ++j)
        cacc[s * 8 + j] += w * (float)af[s][j];
  }

  // reduce context over the 16 rows (l15 lanes) of each quad
  #pragma unroll
  for (int m = 1; m < 16; m <<= 1) {
    #pragma unroll
    for (int k = 0; k < 32; ++k)
      cacc[k] += __shfl_xor(cacc[k], m, 64);
  }
  // L: reduce over l15 bits (quads hold identical copies)
  Lpart += __shfl_xor(Lpart, 1, 64);
  Lpart += __shfl_xor(Lpart, 2, 64);
  Lpart += __shfl_xor(Lpart, 4, 64);
  Lpart += __shfl_xor(Lpart, 8, 64);

  __syncthreads();                   // all ldsW reads done; reuse as pcbuf
  float* pcbuf = (float*)ldsW;       // [4][128]
  if (l15 == 0) {
    #pragma unroll
    for (int s = 0; s < 4; ++s)
      #pragma unroll
      for (int j = 0; j < 8; ++j)
        pcbuf[wave * H_ + s * 32 + quad * 8 + j] = cacc[s * 8 + j];
  }
  if (lane == 0) lsum[wave] = Lpart;
  __syncthreads();

  // per-block partial stores -- private slots, no atomics
  if (t < H_) {
    float s = pcbuf[0 * H_ + t] + pcbuf[1 * H_ + t] + pcbuf[2 * H_ + t] + pcbuf[3 * H_ + t];
    ws[WS_PC + blockIdx.x * H_ + t] = s;
  }
  if (t == 0)
    ws[WS_PL + blockIdx.x] = lsum[0] + lsum[1] + lsum[2] + lsum[3];
}

// ---------------------------------------------------------------------------
// Finalize: blocks 0..255 -> e = w / L[b] (float4; L = sum of 32 partials,
// computed once per block). Block 256 -> c = (sum of 32 C partials) / L.
// ---------------------------------------------------------------------------
__global__ __launch_bounds__(256) void finalize_kernel(
    float* __restrict__ e, float* __restrict__ c, const float* __restrict__ ws) {
  int t = threadIdx.x;
  if (blockIdx.x < 256) {
    __shared__ float sL;
    int b = blockIdx.x >> 3;           // 8 blocks per batch, batch-aligned
    if (t == 0) {
      float L = 0.f;
      #pragma unroll
      for (int k = 0; k < 32; ++k) L += ws[WS_PL + b * 32 + k];
      sL = L;
    }
    __syncthreads();
    float inv = 1.f / sL;
    int i4 = blockIdx.x * 256 + t;     // 65536 float4 total
    float4 v = ((float4*)e)[i4];
    v.x *= inv; v.y *= inv; v.z *= inv; v.w *= inv;
    ((float4*)e)[i4] = v;
  } else {
    __shared__ float Ls[32];
    if (t < 32) {
      float L = 0.f;
      #pragma unroll
      for (int k = 0; k < 32; ++k) L += ws[WS_PL + t * 32 + k];
      Ls[t] = L;
    }
    __syncthreads();
    #pragma unroll
    for (int kk = 0; kk < 16; ++kk) {
      int i = kk * 256 + t;            // 0..4095
      int bb = i >> 7, h = i & 127;
      float s = 0.f;
      #pragma unroll
      for (int k = 0; k < 32; ++k) s += ws[WS_PC + (bb * 32 + k) * H_ + h];
      c[i] = s / Ls[bb];
    }
  }
}

// ---------------------------------------------------------------------------
extern "C" void kernel_launch(void* const* d_in, const int* in_sizes, int n_in,
                              void* d_out, int out_size, void* d_ws, size_t ws_size,
                              hipStream_t stream) {
  const float* enc = (const float*)d_in[0];  // [32, 8192, 128]
  const float* dec = (const float*)d_in[1];  // [32, 1, 128]
  const float* Wa  = (const float*)d_in[2];  // [128, 128]
  const float* Ua  = (const float*)d_in[3];  // [128, 128]
  const float* Va  = (const float*)d_in[4];  // [128, 1]

  float* out   = (float*)d_out;
  float* e_out = out;               // [32][8192]
  float* c_out = out + B_ * TE_;    // [32][128]
  float* ws    = (float*)d_ws;

  fused_kernel<<<M_ / 256, 256, 0, stream>>>(enc, dec, Wa, Ua, Va, e_out, ws);
  finalize_kernel<<<257, 256, 0, stream>>>(e_out, c_out, ws);
}